// Round 6
// baseline (389.560 us; speedup 1.0000x reference)
//
#include <hip/hip_runtime.h>
#include <hip/hip_bf16.h>

#define NN 4096      // nodes
#define ED 1024      // edim
#define WF 1024      // wfeat
#define SLOPEC 0.01f
#define NEG_INFC -1e9f

typedef __attribute__((ext_vector_type(8))) short bf16x8;
typedef __attribute__((ext_vector_type(4))) short short4v;
typedef __attribute__((ext_vector_type(4))) float f32x4;
typedef __attribute__((ext_vector_type(4))) int int4v;

__device__ __forceinline__ float bf2f(short s) {
    union { unsigned u; float f; } v;
    v.u = ((unsigned)(unsigned short)s) << 16;
    return v.f;
}
__device__ __forceinline__ short f2bf(float f) {
    unsigned u = __float_as_uint(f);
    unsigned r = u + 0x7FFFu + ((u >> 16) & 1u);   // RNE (finite data)
    return (short)(r >> 16);
}

typedef __attribute__((address_space(3))) unsigned lds_u32;
typedef const __attribute__((address_space(1))) unsigned gbl_u32;
__device__ __forceinline__ void g2l16(const short* g, short* l) {
    __builtin_amdgcn_global_load_lds((gbl_u32*)g, (lds_u32*)l, 16, 0, 0);
}

// ---------------------------------------------------------------------------
// Fused prep:
//  blocks [0,256): transpose+convert W [ED][WF] fp32 -> Wt [WF][ED] bf16
//    + partial v_src[k] += sum_f W[k,f]*a_src[f] (v zeroed by prior memset)
//    block 0 additionally zeroes pool (1024 floats)
//  blocks [256,256+NN): gather+convert X[i][k] = bf16(emb[inSen[i]][k])
// ---------------------------------------------------------------------------
__global__ __launch_bounds__(256) void k_prep(const float* __restrict__ W,
                                              short* __restrict__ Wt,
                                              const int* __restrict__ inSen,
                                              const float* __restrict__ emb,
                                              short* __restrict__ X,
                                              const float* __restrict__ a_src,
                                              const float* __restrict__ a_dst,
                                              float* __restrict__ v_src,
                                              float* __restrict__ v_dst,
                                              float* __restrict__ pool) {
    if (blockIdx.x < 256) {
        if (blockIdx.x == 0) {
            f32x4 z = {0.f, 0.f, 0.f, 0.f};
            *(f32x4*)(pool + threadIdx.x * 4) = z;   // 256*4 = 1024 floats
        }
        __shared__ float t[64][65];
        const int n0 = (blockIdx.x & 15) * 64, k0 = (blockIdx.x >> 4) * 64;
        const int tx = threadIdx.x & 63, ty = threadIdx.x >> 6;
#pragma unroll
        for (int p = 0; p < 16; p++) {
            int r = p * 4 + ty;
            t[r][tx] = W[(long)(k0 + r) * WF + n0 + tx];
        }
        __syncthreads();
#pragma unroll
        for (int p = 0; p < 16; p++) {
            int r = p * 4 + ty;  // n index
            Wt[(long)(n0 + r) * ED + k0 + tx] = f2bf(t[tx][r]);
        }
        // partial v_src/v_dst from the LDS-resident W tile:
        // v_src[k0+r] += sum_{f in [n0,n0+64)} W[k0+r][f] * a_src[f]
        const int r = threadIdx.x >> 2, q = threadIdx.x & 3;
        float pvs = 0.f, pvd = 0.f;
#pragma unroll
        for (int j = 0; j < 16; j++) {
            float w = t[r][q * 16 + j];
            pvs += w * a_src[n0 + q * 16 + j];
            pvd += w * a_dst[n0 + q * 16 + j];
        }
        pvs += __shfl_xor(pvs, 1); pvs += __shfl_xor(pvs, 2);
        pvd += __shfl_xor(pvd, 1); pvd += __shfl_xor(pvd, 2);
        if (q == 0) {
            atomicAdd(v_src + k0 + r, pvs);
            atomicAdd(v_dst + k0 + r, pvd);
        }
    } else {
        const int row = blockIdx.x - 256;
        const int tid = threadIdx.x;
        const long idx = inSen[row];
        const float4 v = ((const float4*)(emb + idx * ED))[tid];
        short4v s;
        s.x = f2bf(v.x); s.y = f2bf(v.y); s.z = f2bf(v.z); s.w = f2bf(v.w);
        *(short4v*)(X + (long)row * ED + tid * 4) = s;
    }
}

// ---------------------------------------------------------------------------
// Scores: s_src[i] = X[i,:] . v_src, s_dst[i] = X[i,:] . v_dst
// (algebraic refactor of (X@W)@a = X@(W@a); fp32 v, bf16 X)
// One wave per row, 4 rows per block -> grid NN/4.
// ---------------------------------------------------------------------------
__global__ __launch_bounds__(256) void k_score(const short* __restrict__ X,
                                               const float* __restrict__ v_src,
                                               const float* __restrict__ v_dst,
                                               float* __restrict__ s_src,
                                               float* __restrict__ s_dst) {
    const int wid = threadIdx.x >> 6, lane = threadIdx.x & 63;
    const int row = blockIdx.x * 4 + wid;
    const short* xr = X + (long)row * ED + lane * 16;
    bf16x8 a0 = *(const bf16x8*)xr;
    bf16x8 a1 = *(const bf16x8*)(xr + 8);
    const float* vs = v_src + lane * 16;
    const float* vd = v_dst + lane * 16;
    float ss = 0.f, sd = 0.f;
#pragma unroll
    for (int j = 0; j < 8; j++) {
        float x0 = bf2f(a0[j]), x1 = bf2f(a1[j]);
        ss += x0 * vs[j] + x1 * vs[8 + j];
        sd += x0 * vd[j] + x1 * vd[8 + j];
    }
#pragma unroll
    for (int off = 32; off; off >>= 1) {
        ss += __shfl_xor(ss, off);
        sd += __shfl_xor(sd, off);
    }
    if (lane == 0) { s_src[row] = ss; s_dst[row] = sd; }
}

// ---------------------------------------------------------------------------
// Fused GEMM1 + attn: compute-bound MFMA blocks co-scheduled with
// memory-bound softmax blocks (disjoint pipes -> overlap, m114).
//  blocks [0,512):    GEMM1 Ht[f][i] = sum_k Wt[f][k]*X[i][k]
//                     BM=64 BN=128 BK=64, bf16 store via LDS repack
//  blocks [512,512+NN): masked-softmax row (adj, s_src/s_dst -> attn, attnB)
// launch_bounds(256,4): VGPR<=128 so 4 blocks/CU co-reside (2 GEMM + 2 attn).
// ---------------------------------------------------------------------------
__global__ __launch_bounds__(256, 4) void k_fused(
    const short* __restrict__ Wt, const short* __restrict__ X,
    short* __restrict__ Ht,
    const int* __restrict__ adj,
    const float* __restrict__ s_src, const float* __restrict__ s_dst,
    float* __restrict__ attn, short* __restrict__ attnB) {
    __shared__ __align__(16) short smem[12288];   // (64+128)*64 shorts = 24KB
    const int b = blockIdx.x;
    const int tid = threadIdx.x;

    if (b < 512) {
        // ---------------- GEMM1 path ----------------
        constexpr int BM = 64, BN = 128, TM = 2, TN = 4;
        short* sA = smem;                 // [2][64][32]
        short* sB = smem + BM * 64;       // [2][128][32]
        const int lane = tid & 63;
        const int wid = tid >> 6;
        const int wm = wid >> 1, wn = wid & 1;
        const int n0 = (b & 31) * BN;     // i-tile
        const int m0 = (b >> 5) * BM;     // f-tile
        const int srow = tid >> 2;
        const int sc8 = (tid & 3) * 8;
        const int l15 = lane & 15;
        const int lhi = lane >> 4;

        f32x4 acc[TM][TN];
#pragma unroll
        for (int t = 0; t < TM; t++)
#pragma unroll
            for (int u = 0; u < TN; u++) acc[t][u] = (f32x4){0.f, 0.f, 0.f, 0.f};

        const short* Ab = Wt + (long)(m0 + srow) * ED + sc8;
        const short* Bb = X + (long)(n0 + srow) * ED + sc8;
        const long rstep = (long)64 * ED;

        for (int k0 = 0; k0 < ED; k0 += 64) {
#pragma unroll
            for (int c = 0; c < 2; c++) {
                g2l16(Ab + k0 + c * 32, sA + c * (BM * 32) + (wid * 64) * 8);
#pragma unroll
                for (int p = 0; p < 2; p++)
                    g2l16(Bb + p * rstep + k0 + c * 32,
                          sB + c * (BN * 32) + (p * 256 + wid * 64) * 8);
            }
            __syncthreads();
#pragma unroll
            for (int c = 0; c < 2; c++) {
                bf16x8 af[TM], bfr[TN];
#pragma unroll
                for (int t = 0; t < TM; t++)
                    af[t] = *(const bf16x8*)&sA[c * (BM * 32) +
                            (wm * (BM / 2) + t * 16 + l15) * 32 + lhi * 8];
#pragma unroll
                for (int u = 0; u < TN; u++)
                    bfr[u] = *(const bf16x8*)&sB[c * (BN * 32) +
                             (wn * (BN / 2) + u * 16 + l15) * 32 + lhi * 8];
#pragma unroll
                for (int t = 0; t < TM; t++)
#pragma unroll
                    for (int u = 0; u < TN; u++)
                        acc[t][u] = __builtin_amdgcn_mfma_f32_16x16x32_bf16(
                            af[t], bfr[u], acc[t][u], 0, 0, 0);
            }
            __syncthreads();
        }
        // bf16 repack + store (D map per 16x16: col=l15, row=lhi*4+r)
        short* sT = smem;
#pragma unroll
        for (int t = 0; t < TM; t++)
#pragma unroll
            for (int u = 0; u < TN; u++)
#pragma unroll
                for (int r = 0; r < 4; r++) {
                    int m = wm * (BM / 2) + t * 16 + lhi * 4 + r;
                    int n = wn * (BN / 2) + u * 16 + l15;
                    sT[m * BN + n] = f2bf(acc[t][u][r]);
                }
        __syncthreads();
#pragma unroll
        for (int q = 0; q < BM * BN / 2048; q++) {
            int idx = q * 256 + tid;
            int row = idx / (BN / 8);
            int c8 = (idx % (BN / 8)) * 8;
            *(bf16x8*)(Ht + (long)(m0 + row) * NN + n0 + c8) =
                *(const bf16x8*)&sT[row * BN + c8];
        }
    } else {
        // ---------------- attn path ----------------
        float* wred = (float*)smem;        // [4]
        float* wred2 = (float*)smem + 4;   // [4]
        const int row = b - 512;
        const float ss = s_src[row];
        const int4v* adj4 = (const int4v*)(adj + (long)row * NN);
        const f32x4* sd4 = (const f32x4*)s_dst;
        float v[16];
        float vmax = -3e38f;
#pragma unroll
        for (int c = 0; c < 4; c++) {
            int idx = c * 256 + tid;
            int4v a = __builtin_nontemporal_load(&adj4[idx]);
            f32x4 d = sd4[idx];
            float x0 = ss + d.x; x0 = x0 > 0.f ? x0 : SLOPEC * x0; x0 = a.x > 0 ? x0 : NEG_INFC;
            float x1 = ss + d.y; x1 = x1 > 0.f ? x1 : SLOPEC * x1; x1 = a.y > 0 ? x1 : NEG_INFC;
            float x2 = ss + d.z; x2 = x2 > 0.f ? x2 : SLOPEC * x2; x2 = a.z > 0 ? x2 : NEG_INFC;
            float x3 = ss + d.w; x3 = x3 > 0.f ? x3 : SLOPEC * x3; x3 = a.w > 0 ? x3 : NEG_INFC;
            v[c * 4 + 0] = x0; v[c * 4 + 1] = x1; v[c * 4 + 2] = x2; v[c * 4 + 3] = x3;
            vmax = fmaxf(vmax, fmaxf(fmaxf(x0, x1), fmaxf(x2, x3)));
        }
#pragma unroll
        for (int off = 32; off; off >>= 1) vmax = fmaxf(vmax, __shfl_xor(vmax, off));
        if ((tid & 63) == 0) wred[tid >> 6] = vmax;
        __syncthreads();
        vmax = fmaxf(fmaxf(wred[0], wred[1]), fmaxf(wred[2], wred[3]));

        float sum = 0.f;
#pragma unroll
        for (int c = 0; c < 16; c++) {
            v[c] = __expf(v[c] - vmax);
            sum += v[c];
        }
#pragma unroll
        for (int off = 32; off; off >>= 1) sum += __shfl_xor(sum, off);
        if ((tid & 63) == 0) wred2[tid >> 6] = sum;
        __syncthreads();
        sum = wred2[0] + wred2[1] + wred2[2] + wred2[3];
        const float inv = 1.0f / sum;

        f32x4* o4 = (f32x4*)(attn + (long)row * NN);
        short4v* b4 = (short4v*)(attnB + (long)row * NN);
#pragma unroll
        for (int c = 0; c < 4; c++) {
            int idx = c * 256 + tid;
            f32x4 o;
            o.x = v[c * 4 + 0] * inv; o.y = v[c * 4 + 1] * inv;
            o.z = v[c * 4 + 2] * inv; o.w = v[c * 4 + 3] * inv;
            __builtin_nontemporal_store(o, &o4[idx]);
            short4v sb;
            sb.x = f2bf(o.x); sb.y = f2bf(o.y); sb.z = f2bf(o.z); sb.w = f2bf(o.w);
            b4[idx] = sb;
        }
    }
}

// ---------------------------------------------------------------------------
// GEMM2 (m97 structure, BK=128): C[M][N] = A[M][K]*Bt[N][K], bf16 in,
// direct fp32 store + fused pool colsum. SWAPXY m-fast dispatch.
// ---------------------------------------------------------------------------
template <int BM, int BN>
__global__ __launch_bounds__(256, 2) void gemm_bt2(
    const short* __restrict__ A, const short* __restrict__ Bt,
    int N, int K, void* __restrict__ Cout,
    float* __restrict__ pool) {
    constexpr int TM = BM / 32;
    constexpr int TN = BN / 32;
    __shared__ __align__(16) short smem[(BM + BN) * 128];
    short* sA = smem;                 // [4][BM][32]
    short* sB = smem + BM * 128;      // [4][BN][32]

    const int tid = threadIdx.x;
    const int lane = tid & 63;
    const int wid = tid >> 6;
    const int wm = wid >> 1, wn = wid & 1;
    const int n0 = blockIdx.y * BN;
    const int m0 = blockIdx.x * BM;   // m-fast

    const int srow = tid >> 2;
    const int sc8 = (tid & 3) * 8;
    const int l15 = lane & 15;
    const int lhi = lane >> 4;

    f32x4 acc[TM][TN];
#pragma unroll
    for (int t = 0; t < TM; t++)
#pragma unroll
        for (int u = 0; u < TN; u++) acc[t][u] = (f32x4){0.f, 0.f, 0.f, 0.f};

    const short* Ab = A + (long)(m0 + srow) * K + sc8;
    const short* Bb = Bt + (long)(n0 + srow) * K + sc8;
    const long rstep = (long)64 * K;

    for (int k0 = 0; k0 < K; k0 += 128) {
#pragma unroll
        for (int c = 0; c < 4; c++) {
#pragma unroll
            for (int p = 0; p < BM / 64; p++)
                g2l16(Ab + p * rstep + k0 + c * 32,
                      sA + c * (BM * 32) + (p * 256 + wid * 64) * 8);
#pragma unroll
            for (int p = 0; p < BN / 64; p++)
                g2l16(Bb + p * rstep + k0 + c * 32,
                      sB + c * (BN * 32) + (p * 256 + wid * 64) * 8);
        }
        __syncthreads();
#pragma unroll
        for (int c = 0; c < 4; c++) {
            bf16x8 af[TM], bfr[TN];
#pragma unroll
            for (int t = 0; t < TM; t++)
                af[t] = *(const bf16x8*)&sA[c * (BM * 32) +
                        (wm * (BM / 2) + t * 16 + l15) * 32 + lhi * 8];
#pragma unroll
            for (int u = 0; u < TN; u++)
                bfr[u] = *(const bf16x8*)&sB[c * (BN * 32) +
                         (wn * (BN / 2) + u * 16 + l15) * 32 + lhi * 8];
#pragma unroll
            for (int t = 0; t < TM; t++)
#pragma unroll
                for (int u = 0; u < TN; u++)
                    acc[t][u] = __builtin_amdgcn_mfma_f32_16x16x32_bf16(
                        af[t], bfr[u], acc[t][u], 0, 0, 0);
        }
        __syncthreads();
    }

    float* C = (float*)Cout;
    float pp[TN];
#pragma unroll
    for (int u = 0; u < TN; u++) pp[u] = 0.f;
#pragma unroll
    for (int t = 0; t < TM; t++)
#pragma unroll
        for (int u = 0; u < TN; u++)
#pragma unroll
            for (int r = 0; r < 4; r++) {
                int m = wm * (BM / 2) + t * 16 + lhi * 4 + r;
                int n = wn * (BN / 2) + u * 16 + l15;
                C[(long)(m0 + m) * N + n0 + n] = acc[t][u][r];
                pp[u] += acc[t][u][r];
            }
#pragma unroll
    for (int u = 0; u < TN; u++) {
        pp[u] += __shfl_xor(pp[u], 16);
        pp[u] += __shfl_xor(pp[u], 32);
    }
    if (lane < 16) {
#pragma unroll
        for (int u = 0; u < TN; u++) {
            int n = n0 + wn * (BN / 2) + u * 16 + lane;
            atomicAdd(pool + n, pp[u]);
        }
    }
}

// ---------------------------------------------------------------------------
// pool mean + classifier + 2-way softmax
// ---------------------------------------------------------------------------
__global__ __launch_bounds__(256) void k_final(const float* __restrict__ pool_acc,
                                               const float* __restrict__ clf_w,
                                               const float* __restrict__ clf_b,
                                               float* __restrict__ out_pool,
                                               float* __restrict__ out_label) {
    __shared__ float r0[4], r1[4];
    const int tid = threadIdx.x;
    float l0 = 0.f, l1 = 0.f;
#pragma unroll
    for (int q = 0; q < 4; q++) {
        int f = q * 256 + tid;
        float p = pool_acc[f] * (1.0f / NN);
        out_pool[f] = p;
        l0 += p * clf_w[f * 2 + 0];
        l1 += p * clf_w[f * 2 + 1];
    }
#pragma unroll
    for (int off = 32; off; off >>= 1) {
        l0 += __shfl_xor(l0, off);
        l1 += __shfl_xor(l1, off);
    }
    if ((tid & 63) == 0) { r0[tid >> 6] = l0; r1[tid >> 6] = l1; }
    __syncthreads();
    if (tid == 0) {
        float L0 = r0[0] + r0[1] + r0[2] + r0[3] + clf_b[0];
        float L1 = r1[0] + r1[1] + r1[2] + r1[3] + clf_b[1];
        float m = fmaxf(L0, L1);
        float e0 = __expf(L0 - m), e1 = __expf(L1 - m);
        float s = e0 + e1;
        out_label[0] = e0 / s;
        out_label[1] = e1 / s;
    }
}

// ---------------------------------------------------------------------------
extern "C" void kernel_launch(void* const* d_in, const int* in_sizes, int n_in,
                              void* d_out, int out_size, void* d_ws,
                              size_t ws_size, hipStream_t stream) {
    const int* inSen = (const int*)d_in[0];
    const int* adj = (const int*)d_in[1];
    const float* emb = (const float*)d_in[2];
    const float* W = (const float*)d_in[3];
    const float* a_src = (const float*)d_in[4];
    const float* a_dst = (const float*)d_in[5];
    const float* clf_w = (const float*)d_in[6];
    const float* clf_b = (const float*)d_in[7];

    float* out = (float*)d_out;
    float* out_pool = out;
    float* attn = out + 1024;
    float* sentence = out + 1024 + (long)NN * NN;
    float* out_label = out + 1024 + (long)NN * NN + (long)NN * WF;

    // ws layout:
    //   X     [NN][ED]    bf16   8 MB  @ 0
    //   Wt    [WF][ED]    bf16   2 MB  @ 8 MB
    //   Ht    [WF][NN]    bf16   8 MB  @ 10 MB
    //   attnB [NN][NN]    bf16  33.6MB @ 18 MB
    //   s_src/s_dst/pool/v_src/v_dst @ 52 MB
    char* ws = (char*)d_ws;
    short* X = (short*)ws;
    short* Wt = (short*)(ws + (8l << 20));
    short* Ht = (short*)(ws + (10l << 20));
    short* attnB = (short*)(ws + (18l << 20));
    float* s_src = (float*)(ws + (52l << 20));
    float* s_dst = s_src + NN;
    float* pool = s_dst + NN;
    float* v_src = pool + WF;
    float* v_dst = v_src + ED;

    // v_src/v_dst must be zero before k_prep's partial atomics
    (void)hipMemsetAsync(v_src, 0, 2 * ED * sizeof(float), stream);

    k_prep<<<256 + NN, 256, 0, stream>>>(W, Wt, inSen, emb, X,
                                         a_src, a_dst, v_src, v_dst, pool);

    // scores via s = X @ (W @ a): frees attn from the GEMM1 dependency
    k_score<<<NN / 4, 256, 0, stream>>>(X, v_src, v_dst, s_src, s_dst);

    // GEMM1 (compute-bound) + attn softmax (HBM-bound) co-scheduled
    k_fused<<<512 + NN, 256, 0, stream>>>(Wt, X, Ht, adj, s_src, s_dst,
                                          attn, attnB);

    // GEMM2: sentence[i][f] = sum_k attnB[i][k] * Ht[f][k]
    // M=NN, N=WF, K=NN. BM=64, BN=128 -> 64x8 = 512 blocks (2/CU), m-fast.
    gemm_bt2<64, 128><<<dim3(NN / 64, WF / 128, 1), 256, 0, stream>>>(
        attnB, Ht, WF, NN, sentence, pool);

    k_final<<<1, 256, 0, stream>>>(pool, clf_w, clf_b, out_pool, out_label);
}

// Round 7
// 386.802 us; speedup vs baseline: 1.0071x; 1.0071x over previous
//
#include <hip/hip_runtime.h>
#include <hip/hip_bf16.h>

#define NN 4096      // nodes
#define ED 1024      // edim
#define WF 1024      // wfeat
#define SLOPEC 0.01f
#define NEG_INFC -1e9f

typedef __attribute__((ext_vector_type(8))) short bf16x8;
typedef __attribute__((ext_vector_type(4))) short short4v;
typedef __attribute__((ext_vector_type(4))) float f32x4;
typedef __attribute__((ext_vector_type(4))) int int4v;

__device__ __forceinline__ float bf2f(short s) {
    union { unsigned u; float f; } v;
    v.u = ((unsigned)(unsigned short)s) << 16;
    return v.f;
}
__device__ __forceinline__ short f2bf(float f) {
    unsigned u = __float_as_uint(f);
    unsigned r = u + 0x7FFFu + ((u >> 16) & 1u);   // RNE (finite data)
    return (short)(r >> 16);
}

typedef __attribute__((address_space(3))) unsigned lds_u32;
typedef const __attribute__((address_space(1))) unsigned gbl_u32;
__device__ __forceinline__ void g2l16(const short* g, short* l) {
    __builtin_amdgcn_global_load_lds((gbl_u32*)g, (lds_u32*)l, 16, 0, 0);
}

// ---------------------------------------------------------------------------
// Fused prep:
//  blocks [0,256): transpose+convert W [ED][WF] fp32 -> Wt [WF][ED] bf16
//    blocks [0,9) additionally zero s_src/s_dst/pool (9216 floats)
//  blocks [256,256+NN): gather+convert X[i][k] = bf16(emb[inSen[i]][k])
// ---------------------------------------------------------------------------
__global__ __launch_bounds__(256) void k_prep(const float* __restrict__ W,
                                              short* __restrict__ Wt,
                                              const int* __restrict__ inSen,
                                              const float* __restrict__ emb,
                                              short* __restrict__ X,
                                              float* __restrict__ zbase) {
    if (blockIdx.x < 256) {
        if (blockIdx.x < 9) {
            // zero s_src (NN) + s_dst (NN) + pool (WF) = 9216 floats
            f32x4 z = {0.f, 0.f, 0.f, 0.f};
            *(f32x4*)(zbase + blockIdx.x * 1024 + threadIdx.x * 4) = z;
        }
        __shared__ float t[64][65];
        const int n0 = (blockIdx.x & 15) * 64, k0 = (blockIdx.x >> 4) * 64;
        const int tx = threadIdx.x & 63, ty = threadIdx.x >> 6;
#pragma unroll
        for (int p = 0; p < 16; p++) {
            int r = p * 4 + ty;
            t[r][tx] = W[(long)(k0 + r) * WF + n0 + tx];
        }
        __syncthreads();
#pragma unroll
        for (int p = 0; p < 16; p++) {
            int r = p * 4 + ty;  // n index
            Wt[(long)(n0 + r) * ED + k0 + tx] = f2bf(t[tx][r]);
        }
    } else {
        const int row = blockIdx.x - 256;
        const int tid = threadIdx.x;
        const long idx = inSen[row];
        const float4 v = ((const float4*)(emb + idx * ED))[tid];
        short4v s;
        s.x = f2bf(v.x); s.y = f2bf(v.y); s.z = f2bf(v.z); s.w = f2bf(v.w);
        *(short4v*)(X + (long)row * ED + tid * 4) = s;
    }
}

// ---------------------------------------------------------------------------
// GEMM (m97 structure, BK=128): C[M][N] = A[M][K] * Bt[N][K], bf16 in.
// Tile BM x BN, 256 thr = 4 waves (2x2). global_load_lds width=16.
// BK=128 staged as four [rows][32] sub-chunks -> one barrier pair per 128-K
// (halves the vmcnt-drain count vs BK=64; occupancy unchanged at 2/CU since
// launch_bounds already caps it and LDS 48KB*2 = 96KB < 160KB).
// MFMA k-order preserved -> bit-identical accumulation.
// MODE 0: bf16 C store via LDS repack + fused s_src/s_dst column scores.
// MODE 1: direct fp32 C store + fused pool colsum (atomic on pool only).
// SWAPXY: blockIdx.x indexes M-tiles (m-fast dispatch -> B-panel L2 reuse).
// ---------------------------------------------------------------------------
template <int BM, int BN, int MODE, bool SWAPXY>
__global__ __launch_bounds__(256, 2) void gemm_bt2(
    const short* __restrict__ A, const short* __restrict__ Bt,
    int N, int K, int Kc, void* __restrict__ Cout,
    const float* __restrict__ a_src, const float* __restrict__ a_dst,
    float* __restrict__ s_src, float* __restrict__ s_dst,
    float* __restrict__ pool) {
    constexpr int TM = BM / 32;           // m-frags per wave
    constexpr int TN = BN / 32;           // n-frags per wave
    constexpr int STAGE = (BM + BN) * 128;              // BK=128
    constexpr int SMEMSZ = (MODE == 0 && BM * BN > STAGE) ? BM * BN : STAGE;
    __shared__ __align__(16) short smem[SMEMSZ];
    short* sA = smem;                 // [4][BM][32]
    short* sB = smem + BM * 128;      // [4][BN][32]

    const int tid = threadIdx.x;
    const int lane = tid & 63;
    const int wid = tid >> 6;
    const int wm = wid >> 1, wn = wid & 1;
    const int n0 = (SWAPXY ? blockIdx.y : blockIdx.x) * BN;
    const int m0 = (SWAPXY ? blockIdx.x : blockIdx.y) * BM;
    const int ks = blockIdx.z * Kc;

    const int srow = tid >> 2;        // 0..63
    const int sc8 = (tid & 3) * 8;    // 0,8,16,24
    const int l15 = lane & 15;
    const int lhi = lane >> 4;

    f32x4 acc[TM][TN];
#pragma unroll
    for (int t = 0; t < TM; t++)
#pragma unroll
        for (int u = 0; u < TN; u++) acc[t][u] = (f32x4){0.f, 0.f, 0.f, 0.f};

    const short* Ab = A + (long)(m0 + srow) * K + ks + sc8;
    const short* Bb = Bt + (long)(n0 + srow) * K + ks + sc8;
    const long rstep = (long)64 * K;   // 64 rows

    for (int k0 = 0; k0 < Kc; k0 += 128) {
#pragma unroll
        for (int c = 0; c < 4; c++) {
#pragma unroll
            for (int p = 0; p < BM / 64; p++)
                g2l16(Ab + p * rstep + k0 + c * 32,
                      sA + c * (BM * 32) + (p * 256 + wid * 64) * 8);
#pragma unroll
            for (int p = 0; p < BN / 64; p++)
                g2l16(Bb + p * rstep + k0 + c * 32,
                      sB + c * (BN * 32) + (p * 256 + wid * 64) * 8);
        }
        __syncthreads();   // drains vmcnt for global_load_lds (once per 128-K)

#pragma unroll
        for (int c = 0; c < 4; c++) {
            bf16x8 af[TM], bfr[TN];
#pragma unroll
            for (int t = 0; t < TM; t++)
                af[t] = *(const bf16x8*)&sA[c * (BM * 32) +
                        (wm * (BM / 2) + t * 16 + l15) * 32 + lhi * 8];
#pragma unroll
            for (int u = 0; u < TN; u++)
                bfr[u] = *(const bf16x8*)&sB[c * (BN * 32) +
                         (wn * (BN / 2) + u * 16 + l15) * 32 + lhi * 8];
#pragma unroll
            for (int t = 0; t < TM; t++)
#pragma unroll
                for (int u = 0; u < TN; u++)
                    acc[t][u] = __builtin_amdgcn_mfma_f32_16x16x32_bf16(
                        af[t], bfr[u], acc[t][u], 0, 0, 0);
        }
        __syncthreads();
    }

    // Epilogue. D mapping per 16x16 tile: col = l15, row = lhi*4 + r
    if (MODE == 0) {
        short* sT = smem;   // safe: last loop iteration ended with a barrier
#pragma unroll
        for (int t = 0; t < TM; t++)
#pragma unroll
            for (int u = 0; u < TN; u++)
#pragma unroll
                for (int r = 0; r < 4; r++) {
                    int m = wm * (BM / 2) + t * 16 + lhi * 4 + r;
                    int n = wn * (BN / 2) + u * 16 + l15;
                    sT[m * BN + n] = f2bf(acc[t][u][r]);
                }
        __syncthreads();
        short* C = (short*)Cout;
#pragma unroll
        for (int q = 0; q < BM * BN / 2048; q++) {
            int idx = q * 256 + tid;
            int row = idx / (BN / 8);
            int c8 = (idx % (BN / 8)) * 8;
            *(bf16x8*)(C + (long)(m0 + row) * N + n0 + c8) =
                *(const bf16x8*)&sT[row * BN + c8];
        }
        // s_src[n] += sum_m Ht[m][n]*a_src[m] over this block's m-range
        float ps[TN], pd[TN];
#pragma unroll
        for (int u = 0; u < TN; u++) { ps[u] = 0.f; pd[u] = 0.f; }
#pragma unroll
        for (int t = 0; t < TM; t++)
#pragma unroll
            for (int r = 0; r < 4; r++) {
                int m = m0 + wm * (BM / 2) + t * 16 + lhi * 4 + r;
                float as = a_src[m], ad = a_dst[m];
#pragma unroll
                for (int u = 0; u < TN; u++) {
                    ps[u] += acc[t][u][r] * as;
                    pd[u] += acc[t][u][r] * ad;
                }
            }
#pragma unroll
        for (int u = 0; u < TN; u++) {
            ps[u] += __shfl_xor(ps[u], 16); ps[u] += __shfl_xor(ps[u], 32);
            pd[u] += __shfl_xor(pd[u], 16); pd[u] += __shfl_xor(pd[u], 32);
        }
        if (lane < 16) {
#pragma unroll
            for (int u = 0; u < TN; u++) {
                int n = n0 + wn * (BN / 2) + u * 16 + lane;
                atomicAdd(s_src + n, ps[u]);
                atomicAdd(s_dst + n, pd[u]);
            }
        }
    } else {
        // MODE 1: direct fp32 store (no split-K, no RMW) + pool colsum.
        float* C = (float*)Cout;
        float pp[TN];
#pragma unroll
        for (int u = 0; u < TN; u++) pp[u] = 0.f;
#pragma unroll
        for (int t = 0; t < TM; t++)
#pragma unroll
            for (int u = 0; u < TN; u++)
#pragma unroll
                for (int r = 0; r < 4; r++) {
                    int m = wm * (BM / 2) + t * 16 + lhi * 4 + r;
                    int n = wn * (BN / 2) + u * 16 + l15;
                    C[(long)(m0 + m) * N + n0 + n] = acc[t][u][r];
                    pp[u] += acc[t][u][r];
                }
#pragma unroll
        for (int u = 0; u < TN; u++) {
            pp[u] += __shfl_xor(pp[u], 16);
            pp[u] += __shfl_xor(pp[u], 32);
        }
        if (lane < 16) {
#pragma unroll
            for (int u = 0; u < TN; u++) {
                int n = n0 + wn * (BN / 2) + u * 16 + lane;
                atomicAdd(pool + n, pp[u]);
            }
        }
    }
}

// ---------------------------------------------------------------------------
// Masked softmax row -> attn fp32 (d_out, NT) + attnB bf16 (ws, GEMM2 A)
// ---------------------------------------------------------------------------
__global__ __launch_bounds__(256) void k_attn(const int* __restrict__ adj,
                                              const float* __restrict__ s_src,
                                              const float* __restrict__ s_dst,
                                              float* __restrict__ attn,
                                              short* __restrict__ attnB) {
    __shared__ float wred[4];
    __shared__ float wred2[4];
    const int row = blockIdx.x;
    const int tid = threadIdx.x;
    const float ss = s_src[row];
    const int4v* adj4 = (const int4v*)(adj + (long)row * NN);
    const f32x4* sd4 = (const f32x4*)s_dst;
    float v[16];
    float vmax = -3e38f;
#pragma unroll
    for (int c = 0; c < 4; c++) {
        int idx = c * 256 + tid;
        int4v a = __builtin_nontemporal_load(&adj4[idx]);
        f32x4 d = sd4[idx];
        float x0 = ss + d.x; x0 = x0 > 0.f ? x0 : SLOPEC * x0; x0 = a.x > 0 ? x0 : NEG_INFC;
        float x1 = ss + d.y; x1 = x1 > 0.f ? x1 : SLOPEC * x1; x1 = a.y > 0 ? x1 : NEG_INFC;
        float x2 = ss + d.z; x2 = x2 > 0.f ? x2 : SLOPEC * x2; x2 = a.z > 0 ? x2 : NEG_INFC;
        float x3 = ss + d.w; x3 = x3 > 0.f ? x3 : SLOPEC * x3; x3 = a.w > 0 ? x3 : NEG_INFC;
        v[c * 4 + 0] = x0; v[c * 4 + 1] = x1; v[c * 4 + 2] = x2; v[c * 4 + 3] = x3;
        vmax = fmaxf(vmax, fmaxf(fmaxf(x0, x1), fmaxf(x2, x3)));
    }
#pragma unroll
    for (int off = 32; off; off >>= 1) vmax = fmaxf(vmax, __shfl_xor(vmax, off));
    if ((tid & 63) == 0) wred[tid >> 6] = vmax;
    __syncthreads();
    vmax = fmaxf(fmaxf(wred[0], wred[1]), fmaxf(wred[2], wred[3]));

    float sum = 0.f;
#pragma unroll
    for (int c = 0; c < 16; c++) {
        v[c] = __expf(v[c] - vmax);
        sum += v[c];
    }
#pragma unroll
    for (int off = 32; off; off >>= 1) sum += __shfl_xor(sum, off);
    if ((tid & 63) == 0) wred2[tid >> 6] = sum;
    __syncthreads();
    sum = wred2[0] + wred2[1] + wred2[2] + wred2[3];
    const float inv = 1.0f / sum;

    f32x4* o4 = (f32x4*)(attn + (long)row * NN);
    short4v* b4 = (short4v*)(attnB + (long)row * NN);
#pragma unroll
    for (int c = 0; c < 4; c++) {
        int idx = c * 256 + tid;
        f32x4 o;
        o.x = v[c * 4 + 0] * inv; o.y = v[c * 4 + 1] * inv;
        o.z = v[c * 4 + 2] * inv; o.w = v[c * 4 + 3] * inv;
        __builtin_nontemporal_store(o, &o4[idx]);
        short4v sb;
        sb.x = f2bf(o.x); sb.y = f2bf(o.y); sb.z = f2bf(o.z); sb.w = f2bf(o.w);
        b4[idx] = sb;
    }
}

// ---------------------------------------------------------------------------
// pool mean + classifier + 2-way softmax
// ---------------------------------------------------------------------------
__global__ __launch_bounds__(256) void k_final(const float* __restrict__ pool_acc,
                                               const float* __restrict__ clf_w,
                                               const float* __restrict__ clf_b,
                                               float* __restrict__ out_pool,
                                               float* __restrict__ out_label) {
    __shared__ float r0[4], r1[4];
    const int tid = threadIdx.x;
    float l0 = 0.f, l1 = 0.f;
#pragma unroll
    for (int q = 0; q < 4; q++) {
        int f = q * 256 + tid;
        float p = pool_acc[f] * (1.0f / NN);
        out_pool[f] = p;
        l0 += p * clf_w[f * 2 + 0];
        l1 += p * clf_w[f * 2 + 1];
    }
#pragma unroll
    for (int off = 32; off; off >>= 1) {
        l0 += __shfl_xor(l0, off);
        l1 += __shfl_xor(l1, off);
    }
    if ((tid & 63) == 0) { r0[tid >> 6] = l0; r1[tid >> 6] = l1; }
    __syncthreads();
    if (tid == 0) {
        float L0 = r0[0] + r0[1] + r0[2] + r0[3] + clf_b[0];
        float L1 = r1[0] + r1[1] + r1[2] + r1[3] + clf_b[1];
        float m = fmaxf(L0, L1);
        float e0 = __expf(L0 - m), e1 = __expf(L1 - m);
        float s = e0 + e1;
        out_label[0] = e0 / s;
        out_label[1] = e1 / s;
    }
}

// ---------------------------------------------------------------------------
extern "C" void kernel_launch(void* const* d_in, const int* in_sizes, int n_in,
                              void* d_out, int out_size, void* d_ws,
                              size_t ws_size, hipStream_t stream) {
    const int* inSen = (const int*)d_in[0];
    const int* adj = (const int*)d_in[1];
    const float* emb = (const float*)d_in[2];
    const float* W = (const float*)d_in[3];
    const float* a_src = (const float*)d_in[4];
    const float* a_dst = (const float*)d_in[5];
    const float* clf_w = (const float*)d_in[6];
    const float* clf_b = (const float*)d_in[7];

    float* out = (float*)d_out;
    float* out_pool = out;
    float* attn = out + 1024;
    float* sentence = out + 1024 + (long)NN * NN;
    float* out_label = out + 1024 + (long)NN * NN + (long)NN * WF;

    // ws layout:
    //   X     [NN][ED]    bf16   8 MB  @ 0
    //   Wt    [WF][ED]    bf16   2 MB  @ 8 MB
    //   Ht    [WF][NN]    bf16   8 MB  @ 10 MB
    //   attnB [NN][NN]    bf16  33.6MB @ 18 MB
    //   s_src/s_dst/pool (9216 f, zeroed in k_prep) @ 52 MB
    char* ws = (char*)d_ws;
    short* X = (short*)ws;
    short* Wt = (short*)(ws + (8l << 20));
    short* Ht = (short*)(ws + (10l << 20));
    short* attnB = (short*)(ws + (18l << 20));
    float* s_src = (float*)(ws + (52l << 20));
    float* s_dst = s_src + NN;
    float* pool = s_dst + NN;

    k_prep<<<256 + NN, 256, 0, stream>>>(W, Wt, inSen, emb, X, s_src);

    // GEMM1: Ht[f][i] = sum_k Wt[f][k] * X[i][k]
    // M=WF, N=NN, K=ED; BM=64, BN=128 -> 512 blocks, bf16 out + fused scores
    gemm_bt2<64, 128, 0, false><<<dim3(NN / 128, WF / 64, 1), 256, 0, stream>>>(
        Wt, X, NN, ED, ED, Ht, a_src, a_dst, s_src, s_dst, nullptr);

    k_attn<<<NN, 256, 0, stream>>>(adj, s_src, s_dst, attn, attnB);

    // GEMM2: sentence[i][f] = sum_k attnB[i][k] * Ht[f][k]
    // M=NN, N=WF, K=NN. BM=64, BN=128, no split-K -> 64x8 = 512 blocks
    // (2/CU), m-fast dispatch so 64-block groups share one Ht B-panel.
    // Direct fp32 stores (no memset, no RMW) + fused pool colsum.
    gemm_bt2<64, 128, 1, true><<<dim3(NN / 64, WF / 128, 1), 256, 0, stream>>>(
        attnB, Ht, WF, NN, NN, sentence,
        nullptr, nullptr, nullptr, nullptr, pool);

    k_final<<<1, 256, 0, stream>>>(pool, clf_w, clf_b, out_pool, out_label);
}